// Round 7
// baseline (89.579 us; speedup 1.0000x reference)
//
#include <hip/hip_runtime.h>
#include <hip/hip_cooperative_groups.h>

namespace cg = cooperative_groups;

#define N_NODES 2048
#define F_IN 64
#define C_OUT 8
#define H_HID 32
#define G_NUM 16
#define W2_STRIDE 260   // padded row stride (floats): bank-spread writes, 2-way-free reads

// ===========================================================================
// PRIMARY: single cooperative kernel, 256 blocks x 256 threads, ~51 KB LDS.
//  Phase 0: per-block graph bounds (LDS) + rho weights
//  Phase A: fsum for 8 nodes/block; W2 staged in TWO c-halves (LDS <= 64KB)
//  grid.sync()
//  Phase B: 8 rows/block (wave = row)
//  grid.sync()
//  Phase C: blocks [0,16): per-graph readout (deterministic order)
// ===========================================================================
__global__ __launch_bounds__(256) void fused_kernel(
    const float* __restrict__ x, const float* __restrict__ W1,
    const float* __restrict__ b1, const float* __restrict__ W2,
    const float* __restrict__ b2,
    const float* __restrict__ dist, const float* __restrict__ norm,
    const int* __restrict__ batch,
    const float* __restrict__ rW1, const float* __restrict__ rb1,
    const float* __restrict__ rW2, const float* __restrict__ rb2,
    float* __restrict__ fsum, float* __restrict__ rowout,
    float* __restrict__ out)
{
    __shared__ float  sW2f[H_HID * W2_STRIDE];     // 33.3 KB, one c-half at a time
    __shared__ float2 sW1B[H_HID * F_IN];          // 16 KB  {W1T,b1T}[h][f]
    __shared__ float  sRW1[H_HID], sRB1[H_HID], sRW2[C_OUT * H_HID], sRB2[C_OUT];
    __shared__ int    s_starts[G_NUM + 1];

    const int tid = threadIdx.x;
    const int b   = blockIdx.x;
    cg::grid_group grid = cg::this_grid();

    // ---------------- phase 0: local bounds + rho weights + W1/b1 ----------
    for (int i = tid; i < N_NODES; i += 256) {
        const int cur  = batch[i];
        const int prev = (i == 0) ? -1 : batch[i - 1];
        for (int g = prev + 1; g <= cur; ++g) s_starts[g] = i;
        if (i == N_NODES - 1)
            for (int g = cur + 1; g <= G_NUM; ++g) s_starts[g] = N_NODES;
    }
    if (tid < H_HID) { sRW1[tid] = rW1[tid]; sRB1[tid] = rb1[tid]; }
    if (tid >= 64 && tid < 64 + C_OUT) sRB2[tid - 64] = rb2[tid - 64];
    if (tid >= 128) { const int k = tid - 128;
        sRW2[k] = rW2[k]; sRW2[k + 128] = rW2[k + 128]; }

    #pragma unroll
    for (int k = 0; k < 8; ++k) {
        const int e  = tid + k * 256;          // e = f*32 + h
        const int f_ = e >> 5, h_ = e & 31;
        sW1B[h_ * 64 + f_] = make_float2(W1[e], b1[e]);
    }
    __syncthreads();

    // ---------------- phase A: fsum, nodes b*8 + wv*2 (+1) -----------------
    const int wv = tid >> 6;
    const int f  = tid & 63;
    {
        const int n0 = b * 8 + wv * 2;
        const float xv0 = x[n0 * F_IN + f];
        const float xv1 = x[(n0 + 1) * F_IN + f];

        float4 a00 = {0,0,0,0}, a01 = {0,0,0,0};   // node0: c0-3, c4-7
        float4 a10 = {0,0,0,0}, a11 = {0,0,0,0};   // node1

        #pragma unroll
        for (int half = 0; half < 2; ++half) {
            if (half) __syncthreads();             // drain reads of prev half
            // stage this c-half of W2: [h][f*4+c_local], padded stride
            #pragma unroll
            for (int k = 0; k < 8; ++k) {
                const int q  = tid + k * 256;      // [0,2048) float4 units
                const int ff = q >> 5;
                const int rem = q & 31;
                const int cl = rem >> 3;
                const int h4 = rem & 7;
                const float4 v =
                    ((const float4*)W2)[ff * 64 + (half * 4 + cl) * 8 + h4];
                const int col = ff * 4 + cl;
                const int h0  = h4 * 4;
                sW2f[(h0 + 0) * W2_STRIDE + col] = v.x;
                sW2f[(h0 + 1) * W2_STRIDE + col] = v.y;
                sW2f[(h0 + 2) * W2_STRIDE + col] = v.z;
                sW2f[(h0 + 3) * W2_STRIDE + col] = v.w;
            }
            __syncthreads();

            float4 acc0 = {0,0,0,0}, acc1 = {0,0,0,0};
            #pragma unroll
            for (int h = 0; h < H_HID; ++h) {
                const float2 wb1 = sW1B[h * 64 + f];
                const float rv0 = fmaxf(fmaf(xv0, wb1.x, wb1.y), 0.f);
                const float rv1 = fmaxf(fmaf(xv1, wb1.x, wb1.y), 0.f);
                const float4 w = *(const float4*)&sW2f[h * W2_STRIDE + 4 * f];
                acc0.x += rv0 * w.x; acc0.y += rv0 * w.y;
                acc0.z += rv0 * w.z; acc0.w += rv0 * w.w;
                acc1.x += rv1 * w.x; acc1.y += rv1 * w.y;
                acc1.z += rv1 * w.z; acc1.w += rv1 * w.w;
            }
            if (half == 0) { a00 = acc0; a10 = acc1; }
            else           { a01 = acc0; a11 = acc1; }
        }

        const float4 b2lo = *(const float4*)&b2[f * C_OUT];
        const float4 b2hi = *(const float4*)&b2[f * C_OUT + 4];
        a00.x += b2lo.x; a00.y += b2lo.y; a00.z += b2lo.z; a00.w += b2lo.w;
        a01.x += b2hi.x; a01.y += b2hi.y; a01.z += b2hi.z; a01.w += b2hi.w;
        a10.x += b2lo.x; a10.y += b2lo.y; a10.z += b2lo.z; a10.w += b2lo.w;
        a11.x += b2hi.x; a11.y += b2hi.y; a11.z += b2hi.z; a11.w += b2hi.w;

        float v0[C_OUT] = {a00.x,a00.y,a00.z,a00.w,a01.x,a01.y,a01.z,a01.w};
        float v1[C_OUT] = {a10.x,a10.y,a10.z,a10.w,a11.x,a11.y,a11.z,a11.w};
        #pragma unroll
        for (int c = 0; c < C_OUT; ++c) {
            float s0 = v0[c], s1 = v1[c];
            for (int off = 32; off; off >>= 1) {
                s0 += __shfl_down(s0, off);
                s1 += __shfl_down(s1, off);
            }
            v0[c] = s0; v1[c] = s1;
        }
        if (f == 0) {
            *(float4*)&fsum[n0 * C_OUT]           = make_float4(v0[0],v0[1],v0[2],v0[3]);
            *(float4*)&fsum[n0 * C_OUT + 4]       = make_float4(v0[4],v0[5],v0[6],v0[7]);
            *(float4*)&fsum[(n0 + 1) * C_OUT]     = make_float4(v1[0],v1[1],v1[2],v1[3]);
            *(float4*)&fsum[(n0 + 1) * C_OUT + 4] = make_float4(v1[4],v1[5],v1[6],v1[7]);
        }
    }

    grid.sync();

    // ---------------- phase B: rows b*8 + wv (+4) ---------------------------
    {
        const int lane = tid & 63;
        #pragma unroll
        for (int rr = 0; rr < 2; ++rr) {
            const int i = b * 8 + wv + rr * 4;
            const int g = batch[i];
            const int js = s_starts[g];
            const int je = s_starts[g + 1];

            float acc[C_OUT] = {0.f,0.f,0.f,0.f,0.f,0.f,0.f,0.f};

            for (int j = js + lane; j < je; j += 64) {
                const float d  = dist[i * N_NODES + j];
                const float s  = 1.0f / (1.0f + d);
                const float nv = norm[i * N_NODES + j];
                const float invn = (nv == 0.0f) ? 1.0f : (1.0f / nv);

                float rho[C_OUT];
                #pragma unroll
                for (int c = 0; c < C_OUT; ++c) rho[c] = sRB2[c];

                #pragma unroll
                for (int h = 0; h < H_HID; ++h) {
                    float rh = fmaxf(fmaf(s, sRW1[h], sRB1[h]), 0.f);
                    #pragma unroll
                    for (int c = 0; c < C_OUT; ++c)
                        rho[c] = fmaf(rh, sRW2[c * H_HID + h], rho[c]);
                }

                const float4 f0 = *(const float4*)&fsum[j * C_OUT];
                const float4 f1 = *(const float4*)&fsum[j * C_OUT + 4];
                acc[0] = fmaf(rho[0] * invn, f0.x, acc[0]);
                acc[1] = fmaf(rho[1] * invn, f0.y, acc[1]);
                acc[2] = fmaf(rho[2] * invn, f0.z, acc[2]);
                acc[3] = fmaf(rho[3] * invn, f0.w, acc[3]);
                acc[4] = fmaf(rho[4] * invn, f1.x, acc[4]);
                acc[5] = fmaf(rho[5] * invn, f1.y, acc[5]);
                acc[6] = fmaf(rho[6] * invn, f1.z, acc[6]);
                acc[7] = fmaf(rho[7] * invn, f1.w, acc[7]);
            }

            #pragma unroll
            for (int c = 0; c < C_OUT; ++c) {
                float v = acc[c];
                for (int off = 32; off; off >>= 1) v += __shfl_down(v, off);
                acc[c] = v;
            }
            if (lane == 0) {
                *(float4*)&rowout[i * C_OUT]     = make_float4(acc[0],acc[1],acc[2],acc[3]);
                *(float4*)&rowout[i * C_OUT + 4] = make_float4(acc[4],acc[5],acc[6],acc[7]);
            }
        }
    }

    grid.sync();

    // ---------------- phase C: readout, blocks [0,16) -----------------------
    if (b < G_NUM) {
        const int is = s_starts[b];
        const int ie = s_starts[b + 1];

        float acc[C_OUT] = {0.f,0.f,0.f,0.f,0.f,0.f,0.f,0.f};
        for (int i = is + tid; i < ie; i += 256) {
            const float4 f0 = *(const float4*)&rowout[i * C_OUT];
            const float4 f1 = *(const float4*)&rowout[i * C_OUT + 4];
            acc[0] += f0.x; acc[1] += f0.y; acc[2] += f0.z; acc[3] += f0.w;
            acc[4] += f1.x; acc[5] += f1.y; acc[6] += f1.z; acc[7] += f1.w;
        }

        const int lane = tid & 63, w = tid >> 6;
        float* red = sRW2;   // reuse (no longer needed)
        #pragma unroll
        for (int c = 0; c < C_OUT; ++c) {
            float v = acc[c];
            for (int off = 32; off; off >>= 1) v += __shfl_down(v, off);
            if (lane == 0) red[w * C_OUT + c] = v;
        }
        __syncthreads();
        if (tid < C_OUT)
            out[b * C_OUT + tid] = red[0 * C_OUT + tid] + red[1 * C_OUT + tid]
                                 + red[2 * C_OUT + tid] + red[3 * C_OUT + tid];
    }
}

// ===========================================================================
// FALLBACK: known-good 3-kernel path from R5 (used iff cooperative launch
// fails; decision is deterministic per-call).
// ===========================================================================
__global__ __launch_bounds__(512) void fsum_bounds_kernel(
    const float* __restrict__ x, const float* __restrict__ W1,
    const float* __restrict__ b1, const float* __restrict__ W2,
    const float* __restrict__ b2, float* __restrict__ fsum,
    const int* __restrict__ batch, int* __restrict__ starts)
{
    const int tid = threadIdx.x;

    if (blockIdx.x >= 256) {
        for (int i = tid; i < N_NODES; i += 512) {
            const int cur = batch[i];
            const int prev = (i == 0) ? -1 : batch[i - 1];
            for (int g = prev + 1; g <= cur; ++g) starts[g] = i;
            if (i == N_NODES - 1)
                for (int g = cur + 1; g <= G_NUM; ++g) starts[g] = N_NODES;
        }
        return;
    }

    __shared__ float4 sA[H_HID * F_IN];   // 32 KB
    __shared__ float4 sB[H_HID * F_IN];   // 32 KB
    float* tmp = (float*)sA;

    #pragma unroll
    for (int k = 0; k < 4; ++k) {
        const int e = tid + k * 512;
        const int f_ = e >> 5, h_ = e & 31;
        tmp[h_ * 64 + f_]        = W1[e];
        tmp[2048 + h_ * 64 + f_] = b1[e];
    }
    __syncthreads();

    const int wv = tid >> 6;
    const int f  = tid & 63;
    float w1r[H_HID], b1r[H_HID];
    #pragma unroll
    for (int h = 0; h < H_HID; ++h) {
        w1r[h] = tmp[h * 64 + f];
        b1r[h] = tmp[2048 + h * 64 + f];
    }
    __syncthreads();

    #pragma unroll
    for (int k = 0; k < 8; ++k) {
        const int eb = 4 * (tid + k * 512);
        const float4 v = *(const float4*)&W2[eb];
        const int h0 = eb & 31;
        const int c  = (eb >> 5) & 7;
        const int ff = eb >> 8;
        float* dst = (c < 4) ? (float*)sA : (float*)sB;
        const int cc = c & 3;
        dst[(h0 + 0) * 256 + ff * 4 + cc] = v.x;
        dst[(h0 + 1) * 256 + ff * 4 + cc] = v.y;
        dst[(h0 + 2) * 256 + ff * 4 + cc] = v.z;
        dst[(h0 + 3) * 256 + ff * 4 + cc] = v.w;
    }
    __syncthreads();

    const int n = blockIdx.x * 8 + wv;
    const float xv = x[n * F_IN + f];
    const float4 b2lo = *(const float4*)&b2[f * C_OUT];
    const float4 b2hi = *(const float4*)&b2[f * C_OUT + 4];

    float4 acc0 = {0,0,0,0}, acc1 = {0,0,0,0};
    #pragma unroll
    for (int h = 0; h < H_HID; ++h) {
        float rv = fmaxf(fmaf(xv, w1r[h], b1r[h]), 0.f);
        const float4 wa = sA[h * 64 + f];
        const float4 wb = sB[h * 64 + f];
        acc0.x += rv * wa.x; acc0.y += rv * wa.y;
        acc0.z += rv * wa.z; acc0.w += rv * wa.w;
        acc1.x += rv * wb.x; acc1.y += rv * wb.y;
        acc1.z += rv * wb.z; acc1.w += rv * wb.w;
    }
    acc0.x += b2lo.x; acc0.y += b2lo.y; acc0.z += b2lo.z; acc0.w += b2lo.w;
    acc1.x += b2hi.x; acc1.y += b2hi.y; acc1.z += b2hi.z; acc1.w += b2hi.w;

    float a[C_OUT] = {acc0.x, acc0.y, acc0.z, acc0.w,
                      acc1.x, acc1.y, acc1.z, acc1.w};
    #pragma unroll
    for (int c = 0; c < C_OUT; ++c) {
        float v = a[c];
        for (int off = 32; off; off >>= 1) v += __shfl_down(v, off);
        a[c] = v;
    }
    if (f == 0) {
        *(float4*)&fsum[n * C_OUT]     = make_float4(a[0], a[1], a[2], a[3]);
        *(float4*)&fsum[n * C_OUT + 4] = make_float4(a[4], a[5], a[6], a[7]);
    }
}

__global__ __launch_bounds__(256) void row_kernel(
    const float* __restrict__ dist, const float* __restrict__ norm,
    const int* __restrict__ batch, const int* __restrict__ starts,
    const float* __restrict__ rW1, const float* __restrict__ rb1,
    const float* __restrict__ rW2, const float* __restrict__ rb2,
    const float* __restrict__ fsum, float* __restrict__ rowout)
{
    const int tid = threadIdx.x;

    __shared__ float sW1[H_HID], sb1[H_HID], sW2[C_OUT * H_HID], sb2[C_OUT];
    if (tid < H_HID) { sW1[tid] = rW1[tid]; sb1[tid] = rb1[tid]; }
    if (tid >= 64 && tid < 64 + C_OUT) sb2[tid - 64] = rb2[tid - 64];
    if (tid >= 128) { const int k = tid - 128;
        sW2[k] = rW2[k]; sW2[k + 128] = rW2[k + 128]; }
    __syncthreads();

    const int wv = tid >> 6, lane = tid & 63;
    const int i = blockIdx.x * 4 + wv;
    const int g = batch[i];
    const int js = starts[g];
    const int je = starts[g + 1];

    float acc[C_OUT] = {0.f,0.f,0.f,0.f,0.f,0.f,0.f,0.f};

    for (int j = js + lane; j < je; j += 64) {
        const float d  = dist[i * N_NODES + j];
        const float s  = 1.0f / (1.0f + d);
        const float nv = norm[i * N_NODES + j];
        const float invn = (nv == 0.0f) ? 1.0f : (1.0f / nv);

        float rho[C_OUT];
        #pragma unroll
        for (int c = 0; c < C_OUT; ++c) rho[c] = sb2[c];

        #pragma unroll
        for (int h = 0; h < H_HID; ++h) {
            float rh = fmaxf(fmaf(s, sW1[h], sb1[h]), 0.f);
            #pragma unroll
            for (int c = 0; c < C_OUT; ++c)
                rho[c] = fmaf(rh, sW2[c * H_HID + h], rho[c]);
        }

        const float4 f0 = *(const float4*)&fsum[j * C_OUT];
        const float4 f1 = *(const float4*)&fsum[j * C_OUT + 4];
        acc[0] = fmaf(rho[0] * invn, f0.x, acc[0]);
        acc[1] = fmaf(rho[1] * invn, f0.y, acc[1]);
        acc[2] = fmaf(rho[2] * invn, f0.z, acc[2]);
        acc[3] = fmaf(rho[3] * invn, f0.w, acc[3]);
        acc[4] = fmaf(rho[4] * invn, f1.x, acc[4]);
        acc[5] = fmaf(rho[5] * invn, f1.y, acc[5]);
        acc[6] = fmaf(rho[6] * invn, f1.z, acc[6]);
        acc[7] = fmaf(rho[7] * invn, f1.w, acc[7]);
    }

    #pragma unroll
    for (int c = 0; c < C_OUT; ++c) {
        float v = acc[c];
        for (int off = 32; off; off >>= 1) v += __shfl_down(v, off);
        acc[c] = v;
    }
    if (lane == 0) {
        *(float4*)&rowout[i * C_OUT]     = make_float4(acc[0],acc[1],acc[2],acc[3]);
        *(float4*)&rowout[i * C_OUT + 4] = make_float4(acc[4],acc[5],acc[6],acc[7]);
    }
}

__global__ __launch_bounds__(64) void readout_kernel(
    const float* __restrict__ rowout, const int* __restrict__ starts,
    float* __restrict__ out)
{
    const int g = blockIdx.x;
    const int tid = threadIdx.x;
    const int is = starts[g];
    const int ie = starts[g + 1];

    float acc[C_OUT] = {0.f,0.f,0.f,0.f,0.f,0.f,0.f,0.f};
    for (int i = is + tid; i < ie; i += 64) {
        const float4 f0 = *(const float4*)&rowout[i * C_OUT];
        const float4 f1 = *(const float4*)&rowout[i * C_OUT + 4];
        acc[0] += f0.x; acc[1] += f0.y; acc[2] += f0.z; acc[3] += f0.w;
        acc[4] += f1.x; acc[5] += f1.y; acc[6] += f1.z; acc[7] += f1.w;
    }

    #pragma unroll
    for (int c = 0; c < C_OUT; ++c) {
        float v = acc[c];
        for (int off = 32; off; off >>= 1) v += __shfl_down(v, off);
        if (tid == 0) out[g * C_OUT + c] = v;
    }
}

extern "C" void kernel_launch(void* const* d_in, const int* in_sizes, int n_in,
                              void* d_out, int out_size, void* d_ws, size_t ws_size,
                              hipStream_t stream)
{
    const float* x    = (const float*)d_in[0];
    const float* dist = (const float*)d_in[1];
    const float* norm = (const float*)d_in[2];
    const int*   batch= (const int*)d_in[3];
    const float* fsW1 = (const float*)d_in[4];
    const float* fsb1 = (const float*)d_in[5];
    const float* fsW2 = (const float*)d_in[6];
    const float* fsb2 = (const float*)d_in[7];
    const float* rW1  = (const float*)d_in[8];
    const float* rb1  = (const float*)d_in[9];
    const float* rW2  = (const float*)d_in[10];
    const float* rb2  = (const float*)d_in[11];
    float* out = (float*)d_out;

    float* fsum   = (float*)d_ws;                       // N*C floats
    float* rowout = fsum + N_NODES * C_OUT;             // N*C floats
    int*   starts = (int*)(rowout + N_NODES * C_OUT);   // G+1 ints (fallback)

    void* args[] = {
        (void*)&x, (void*)&fsW1, (void*)&fsb1, (void*)&fsW2, (void*)&fsb2,
        (void*)&dist, (void*)&norm, (void*)&batch,
        (void*)&rW1, (void*)&rb1, (void*)&rW2, (void*)&rb2,
        (void*)&fsum, (void*)&rowout, (void*)&out
    };
    hipError_t err = hipLaunchCooperativeKernel((void*)fused_kernel,
                                                dim3(256), dim3(256),
                                                args, 0, stream);
    if (err != hipSuccess) {
        (void)hipGetLastError();   // clear sticky error, use fallback path
        fsum_bounds_kernel<<<257, 512, 0, stream>>>(x, fsW1, fsb1, fsW2, fsb2,
                                                    fsum, batch, starts);
        row_kernel<<<N_NODES / 4, 256, 0, stream>>>(dist, norm, batch, starts,
                                                    rW1, rb1, rW2, rb2, fsum, rowout);
        readout_kernel<<<G_NUM, 64, 0, stream>>>(rowout, starts, out);
    }
}

// Round 8
// 23.619 us; speedup vs baseline: 3.7927x; 3.7927x over previous
//
#include <hip/hip_runtime.h>

#define N_NODES 2048
#define F_IN 64
#define C_OUT 8
#define H_HID 32
#define G_NUM 16

// ---------------------------------------------------------------------------
// K1: blocks [0,256): fsum for 8 nodes each (4 waves, lane=feature, 2 nodes
//     per lane). Block 256: graph bounds + zero out[].
//
// fsum[n,c] = sum_f ( relu(x[n,f]*W1[f,:]+b1[f,:]) . W2[f,c,:] + b2[f,c] )
//
//  - W1/b1 transposed via padded LDS (stride 65) -> registers (static index)
//  - W2 staged in sA/sB [h][ 4*(f^ (h>>2)) + c ] XOR swizzle:
//      staging writes: 32 distinct banks per 32 lanes, 2-way across halves -> free
//      compute reads: lane-permutation of consecutive 16B blocks -> conflict-free b128
// ---------------------------------------------------------------------------
__global__ __launch_bounds__(256) void fsum_bounds_kernel(
    const float* __restrict__ x, const float* __restrict__ W1,
    const float* __restrict__ b1, const float* __restrict__ W2,
    const float* __restrict__ b2, float* __restrict__ fsum,
    const int* __restrict__ batch, int* __restrict__ starts,
    float* __restrict__ out)
{
    const int tid = threadIdx.x;

    if (blockIdx.x >= 256) {
        for (int i = tid; i < N_NODES; i += 256) {
            const int cur  = batch[i];
            const int prev = (i == 0) ? -1 : batch[i - 1];
            for (int g = prev + 1; g <= cur; ++g) starts[g] = i;
            if (i == N_NODES - 1)
                for (int g = cur + 1; g <= G_NUM; ++g) starts[g] = N_NODES;
        }
        if (tid < G_NUM * C_OUT) out[tid] = 0.0f;   // zero accumulator target
        return;
    }

    __shared__ float sA[H_HID * 256];   // 32 KB : W2 c0..3, swizzled
    __shared__ float sB[H_HID * 256];   // 32 KB : W2 c4..7, swizzled
    float* tmp = sA;                    // transient W1T/b1T staging

    // ---- stage W1T/b1T (padded stride 65: conflict-free) ----
    #pragma unroll
    for (int k = 0; k < 8; ++k) {
        const int e  = tid + k * 256;          // e = f*32 + h
        const int f_ = e >> 5, h_ = e & 31;
        tmp[h_ * 65 + f_]        = W1[e];
        tmp[2080 + h_ * 65 + f_] = b1[e];
    }
    __syncthreads();

    const int wv = tid >> 6;                   // wave -> node pair
    const int f  = tid & 63;                   // lane -> feature
    float w1r[H_HID], b1r[H_HID];
    #pragma unroll
    for (int h = 0; h < H_HID; ++h) {
        w1r[h] = tmp[h * 65 + f];
        b1r[h] = tmp[2080 + h * 65 + f];
    }
    __syncthreads();                           // regs loaded; sA reusable

    // ---- stage W2 with XOR swizzle ----
    #pragma unroll
    for (int k = 0; k < 16; ++k) {
        const int q = tid + k * 256;           // float4 index, 0..4095
        const float4 v = *(const float4*)&W2[4 * q];
        const int h0 = (q & 7) * 4;            // h0 = 4*(q&7); h>>2 == q&7
        const int c  = (q >> 3) & 7;
        const int ff = q >> 6;
        float* dst = (c < 4) ? sA : sB;
        const int col = (ff * 4 + (c & 3)) ^ ((q & 7) << 2);
        dst[(h0 + 0) * 256 + col] = v.x;
        dst[(h0 + 1) * 256 + col] = v.y;
        dst[(h0 + 2) * 256 + col] = v.z;
        dst[(h0 + 3) * 256 + col] = v.w;
    }
    __syncthreads();

    // ---- compute: 2 nodes per lane ----
    const int n0 = blockIdx.x * 8 + wv * 2;
    const float xv0 = x[n0 * F_IN + f];
    const float xv1 = x[n0 * F_IN + F_IN + f];

    float4 a00 = {0,0,0,0}, a01 = {0,0,0,0};
    float4 a10 = {0,0,0,0}, a11 = {0,0,0,0};

    #pragma unroll
    for (int h = 0; h < H_HID; ++h) {
        const float rv0 = fmaxf(fmaf(xv0, w1r[h], b1r[h]), 0.f);
        const float rv1 = fmaxf(fmaf(xv1, w1r[h], b1r[h]), 0.f);
        const int colx = (4 * f) ^ ((h >> 2) << 2);
        const float4 wa = *(const float4*)&sA[h * 256 + colx];
        const float4 wb = *(const float4*)&sB[h * 256 + colx];
        a00.x = fmaf(rv0, wa.x, a00.x); a00.y = fmaf(rv0, wa.y, a00.y);
        a00.z = fmaf(rv0, wa.z, a00.z); a00.w = fmaf(rv0, wa.w, a00.w);
        a01.x = fmaf(rv0, wb.x, a01.x); a01.y = fmaf(rv0, wb.y, a01.y);
        a01.z = fmaf(rv0, wb.z, a01.z); a01.w = fmaf(rv0, wb.w, a01.w);
        a10.x = fmaf(rv1, wa.x, a10.x); a10.y = fmaf(rv1, wa.y, a10.y);
        a10.z = fmaf(rv1, wa.z, a10.z); a10.w = fmaf(rv1, wa.w, a10.w);
        a11.x = fmaf(rv1, wb.x, a11.x); a11.y = fmaf(rv1, wb.y, a11.y);
        a11.z = fmaf(rv1, wb.z, a11.z); a11.w = fmaf(rv1, wb.w, a11.w);
    }
    const float4 b2lo = *(const float4*)&b2[f * C_OUT];
    const float4 b2hi = *(const float4*)&b2[f * C_OUT + 4];
    a00.x += b2lo.x; a00.y += b2lo.y; a00.z += b2lo.z; a00.w += b2lo.w;
    a01.x += b2hi.x; a01.y += b2hi.y; a01.z += b2hi.z; a01.w += b2hi.w;
    a10.x += b2lo.x; a10.y += b2lo.y; a10.z += b2lo.z; a10.w += b2lo.w;
    a11.x += b2hi.x; a11.y += b2hi.y; a11.z += b2hi.z; a11.w += b2hi.w;

    float v0[C_OUT] = {a00.x,a00.y,a00.z,a00.w,a01.x,a01.y,a01.z,a01.w};
    float v1[C_OUT] = {a10.x,a10.y,a10.z,a10.w,a11.x,a11.y,a11.z,a11.w};
    #pragma unroll
    for (int c = 0; c < C_OUT; ++c) {
        float s0 = v0[c], s1 = v1[c];
        for (int off = 32; off; off >>= 1) {
            s0 += __shfl_down(s0, off);
            s1 += __shfl_down(s1, off);
        }
        v0[c] = s0; v1[c] = s1;
    }
    if (f == 0) {
        *(float4*)&fsum[n0 * C_OUT]           = make_float4(v0[0],v0[1],v0[2],v0[3]);
        *(float4*)&fsum[n0 * C_OUT + 4]       = make_float4(v0[4],v0[5],v0[6],v0[7]);
        *(float4*)&fsum[(n0 + 1) * C_OUT]     = make_float4(v1[0],v1[1],v1[2],v1[3]);
        *(float4*)&fsum[(n0 + 1) * C_OUT + 4] = make_float4(v1[4],v1[5],v1[6],v1[7]);
    }
}

// ---------------------------------------------------------------------------
// K2: 512 blocks x 256 thr, wave = row (4 rows/block). Computes
//   row_i[c] = sum_{j in graph(i)} rho(i,j,c)/norm_safe * fsum[j,c]
// then block-level LDS reduction per graph and atomic accumulation into out.
// ---------------------------------------------------------------------------
__global__ __launch_bounds__(256) void row_readout_kernel(
    const float* __restrict__ dist, const float* __restrict__ norm,
    const int* __restrict__ batch, const int* __restrict__ starts,
    const float* __restrict__ rW1, const float* __restrict__ rb1,
    const float* __restrict__ rW2, const float* __restrict__ rb2,
    const float* __restrict__ fsum, float* __restrict__ out)
{
    const int tid = threadIdx.x;

    __shared__ float sW1[H_HID], sb1[H_HID], sW2[C_OUT * H_HID], sb2[C_OUT];
    __shared__ float sRow[4][C_OUT];
    __shared__ int   sG[4];
    if (tid < H_HID) { sW1[tid] = rW1[tid]; sb1[tid] = rb1[tid]; }
    if (tid >= 64 && tid < 64 + C_OUT) sb2[tid - 64] = rb2[tid - 64];
    if (tid >= 128) { const int k = tid - 128;
        sW2[k] = rW2[k]; sW2[k + 128] = rW2[k + 128]; }
    __syncthreads();

    const int wv = tid >> 6, lane = tid & 63;
    const int i = blockIdx.x * 4 + wv;
    const int g = batch[i];
    const int js = starts[g];
    const int je = starts[g + 1];

    float acc[C_OUT] = {0.f,0.f,0.f,0.f,0.f,0.f,0.f,0.f};

    for (int j = js + lane; j < je; j += 64) {
        const float d  = dist[i * N_NODES + j];
        const float s  = 1.0f / (1.0f + d);
        const float nv = norm[i * N_NODES + j];
        const float invn = (nv == 0.0f) ? 1.0f : (1.0f / nv);

        float rho[C_OUT];
        #pragma unroll
        for (int c = 0; c < C_OUT; ++c) rho[c] = sb2[c];

        #pragma unroll
        for (int h = 0; h < H_HID; ++h) {
            const float rh = fmaxf(fmaf(s, sW1[h], sb1[h]), 0.f);
            #pragma unroll
            for (int c = 0; c < C_OUT; ++c)
                rho[c] = fmaf(rh, sW2[c * H_HID + h], rho[c]);
        }

        const float4 f0 = *(const float4*)&fsum[j * C_OUT];
        const float4 f1 = *(const float4*)&fsum[j * C_OUT + 4];
        acc[0] = fmaf(rho[0] * invn, f0.x, acc[0]);
        acc[1] = fmaf(rho[1] * invn, f0.y, acc[1]);
        acc[2] = fmaf(rho[2] * invn, f0.z, acc[2]);
        acc[3] = fmaf(rho[3] * invn, f0.w, acc[3]);
        acc[4] = fmaf(rho[4] * invn, f1.x, acc[4]);
        acc[5] = fmaf(rho[5] * invn, f1.y, acc[5]);
        acc[6] = fmaf(rho[6] * invn, f1.z, acc[6]);
        acc[7] = fmaf(rho[7] * invn, f1.w, acc[7]);
    }

    #pragma unroll
    for (int c = 0; c < C_OUT; ++c) {
        float v = acc[c];
        for (int off = 32; off; off >>= 1) v += __shfl_down(v, off);
        acc[c] = v;
    }
    if (lane == 0) {
        *(float4*)&sRow[wv][0] = make_float4(acc[0],acc[1],acc[2],acc[3]);
        *(float4*)&sRow[wv][4] = make_float4(acc[4],acc[5],acc[6],acc[7]);
        sG[wv] = g;
    }
    __syncthreads();

    // per-block graph-partial accumulation (<= 2 graphs typical, generic loop)
    if (tid < C_OUT) {
        const int c  = tid;
        const int gF = sG[0], gL = sG[3];
        for (int gg = gF; gg <= gL; ++gg) {
            float s = 0.f;
            bool any = false;
            #pragma unroll
            for (int r = 0; r < 4; ++r)
                if (sG[r] == gg) { s += sRow[r][c]; any = true; }
            if (any) unsafeAtomicAdd(&out[gg * C_OUT + c], s);
        }
    }
}

extern "C" void kernel_launch(void* const* d_in, const int* in_sizes, int n_in,
                              void* d_out, int out_size, void* d_ws, size_t ws_size,
                              hipStream_t stream)
{
    const float* x    = (const float*)d_in[0];
    const float* dist = (const float*)d_in[1];
    const float* norm = (const float*)d_in[2];
    const int*   batch= (const int*)d_in[3];
    const float* fsW1 = (const float*)d_in[4];
    const float* fsb1 = (const float*)d_in[5];
    const float* fsW2 = (const float*)d_in[6];
    const float* fsb2 = (const float*)d_in[7];
    const float* rW1  = (const float*)d_in[8];
    const float* rb1  = (const float*)d_in[9];
    const float* rW2  = (const float*)d_in[10];
    const float* rb2  = (const float*)d_in[11];
    float* out = (float*)d_out;

    float* fsum   = (float*)d_ws;                     // N*C floats
    int*   starts = (int*)(fsum + N_NODES * C_OUT);   // G+1 ints

    fsum_bounds_kernel<<<257, 256, 0, stream>>>(x, fsW1, fsb1, fsW2, fsb2,
                                                fsum, batch, starts, out);
    row_readout_kernel<<<N_NODES / 4, 256, 0, stream>>>(dist, norm, batch, starts,
                                                        rW1, rb1, rW2, rb2,
                                                        fsum, out);
}